// Round 8
// baseline (345.461 us; speedup 1.0000x reference)
//
#include <hip/hip_runtime.h>

// ---------------------------------------------------------------------------
// Attention_4956392259713 — round 15: per-kernel DEPTH + fused rowsum + merged QKV.
// qkv = x@W^T+b; S = q@k^T (unscaled); P = softmax(S); out = P@v
//
// R14 post-mortem: total 319 (best) but K2 regressed 69->80 under 3-buf
// counted vmcnt while K1a/K4 improved. 7 structures all pin MfmaUtil 27-31%:
// structure is a per-kernel +-10% knob, not the 2x lever. This round cuts
// work/launches and assigns measured-best schedule per kernel:
//  1) DEPTH template: K2=2-buf (R12-best), QKV/K4=3-buf counted (R14-best).
//  2) rowsum fused into K2 epilogue: sum the BF16-ROUNDED E (bit-identical
//     denominator to the old kernel), shfl_xor reduce over the 16-lane col
//     group, one atomicAdd per row per wave; r zeroed via hipMemsetAsync;
//     K4 multiplies by exact 1.0f/r[row]. Removes rowsum launch + 67MB read.
//  3) K1a+K1b merged (MODE 5, N=2304, grid 9x64): bx<6 -> fp16 qk (ldc 1536),
//     bx>=6 -> bf16 v (ldc 768). Removes a launch + K1b's 0.75 blk/CU tail.
// Core loops unchanged from their best measured variants (0 bank conflicts).
// Swizzle (64B rows): 16B-unit U=u^((row>>1)&3); write = linear gld16 dest +
// pre-swizzled GLOBAL column (rule #21); read folded into per-lane ku.
// Numerics: fp16 QKV/QK^T; bf16 E and PV; no max subtraction (logits ~55).
// Fragment maps (m89-verified): A/B idx=lane&15, k=(lane>>4)*8+j;
//                               C/D col=lane&15, row=(lane>>4)*4+reg.
// ---------------------------------------------------------------------------

typedef short    s16x8 __attribute__((ext_vector_type(8)));
typedef _Float16 h16x8 __attribute__((ext_vector_type(8)));
typedef _Float16 h16x4 __attribute__((ext_vector_type(4)));
typedef float    f32x4 __attribute__((ext_vector_type(4)));

__device__ __forceinline__ unsigned short f2bf(float x) {
    unsigned u = __float_as_uint(x);
    u += 0x7fffu + ((u >> 16) & 1u);          // RTNE
    return (unsigned short)(u >> 16);
}
__device__ __forceinline__ float bf2f(unsigned short h) {
    return __uint_as_float(((unsigned)h) << 16);
}
__device__ __forceinline__ unsigned short f2h(float x) {
    _Float16 h = (_Float16)x;                 // v_cvt_f16_f32, RTNE
    unsigned short u;
    __builtin_memcpy(&u, &h, 2);
    return u;
}
__device__ __forceinline__ h16x8 as_h(s16x8 v) {
    h16x8 r; __builtin_memcpy(&r, &v, 16); return r;
}

// async global->LDS, 16 B per lane; LDS dest = wave-uniform base + lane*16
__device__ __forceinline__ void gld16(const void* g, void* l) {
    __builtin_amdgcn_global_load_lds(
        (const __attribute__((address_space(1))) unsigned int*)(unsigned long long)g,
        (__attribute__((address_space(3))) unsigned int*)(unsigned)(unsigned long long)l,
        16, 0, 0);
}

template<bool FP16>
__device__ __forceinline__ f32x4 mma(s16x8 a, s16x8 b, f32x4 c) {
    if constexpr (FP16)
        return __builtin_amdgcn_mfma_f32_16x16x32_f16(as_h(a), as_h(b), c, 0, 0, 0);
    else
        return __builtin_amdgcn_mfma_f32_16x16x32_bf16(a, b, c, 0, 0, 0);
}

// NT GEMM, 512 thr = 8 waves (2Mx4N), tile 256x256, BK=32.
// MODE 3: C = exp(acc) -> bf16, fused row-sum atomics  [K2]
// MODE 4: C = acc * (1/rvec[row]) -> f32               [K4]
// MODE 5: C = acc + bias -> fp16 (cols<1536, ldc 1536) or bf16 (ldc 768) [QKV]
// SWZ 1: 3D batch-per-XCD; 2: 2D row-chunk-per-XCD (gridDim.y%8==0)
// DEPTH 2: dbuf, stage t+1 @top, vmcnt(0) @end (R12 schedule)
// DEPTH 3: 3-buf, stage t+2 @top, vmcnt(4) @end — counted, never 0 (R14)
template<int MODE, bool FP16, int SWZ, int DEPTH>
__global__ __launch_bounds__(512, 2)
void gemm_mfma(const unsigned short* __restrict__ A, const unsigned short* __restrict__ B,
               const float* __restrict__ bias, const float* __restrict__ rvec,
               float* __restrict__ rsum,
               float* __restrict__ Cf, unsigned short* __restrict__ Ch,
               unsigned short* __restrict__ Ch2,
               int K, int lda, int ldb, int ldc,
               long long sA, long long sB, long long sC, long long sR)
{
    __shared__ unsigned short As[DEPTH][8192];   // [256 rows][32 k] 2B, swizzled
    __shared__ unsigned short Bs[DEPTH][8192];

    int bx = blockIdx.x, by = blockIdx.y, bz = blockIdx.z;
    if (SWZ == 1) {
        const int l = bx + gridDim.x * (by + gridDim.y * bz);
        bz = l & 7;
        const int t = l >> 3;
        bx = t % gridDim.x;
        by = t / gridDim.x;
    } else if (SWZ == 2) {
        const int l = bx + gridDim.x * by;
        const int c = l & 7;
        const int t = l >> 3;
        const int rows = gridDim.y >> 3;
        bx = t % gridDim.x;
        by = c * rows + t / gridDim.x;
    }

    A += (long long)bz * sA;
    B += (long long)bz * sB;

    const long long m0 = (long long)by * 256;
    const long long n0 = (long long)bx * 256;

    const int tid  = threadIdx.x;
    const int wave = tid >> 6, lane = tid & 63;
    const int wr = wave >> 2, wc = wave & 3;             // 2M x 4N wave grid
    const int ml = lane & 15;                            // fragment row-in-16
    // swizzled k-unit for fragment reads: U = u ^ ((row>>1)&3)
    const int ku = (((lane >> 4) ^ ((ml >> 1) & 3)) * 8);
    const int srr = wave * 16 + (lane >> 2);             // staging row 0..127
    // pre-swizzled GLOBAL column (write side; gld16 LDS dest stays linear)
    const int skc = (((lane & 3) ^ ((lane >> 3) & 3)) * 8);

    const int aidx = (wr * 128 + ml) * 32 + ku;          // LDS elem index
    const int bidx = (wc * 64  + ml) * 32 + ku;

    const unsigned short* Abase = A + (m0 + srr) * (long long)lda + skc;
    const unsigned short* Bbase = B + (n0 + srr) * (long long)ldb + skc;
    const long long a128 = 128LL * lda, b128 = 128LL * ldb;

    auto stage_a = [&](int t, int buf) {
        const unsigned short* p = Abase + t * 32;
        gld16(p,        &As[buf][wave * 512]);
        gld16(p + a128, &As[buf][4096 + wave * 512]);
    };
    auto stage_b = [&](int t, int buf) {
        const unsigned short* p = Bbase + t * 32;
        gld16(p,        &Bs[buf][wave * 512]);
        gld16(p + b128, &Bs[buf][4096 + wave * 512]);
    };

    f32x4 acc[8][4];
#pragma unroll
    for (int i = 0; i < 8; ++i)
#pragma unroll
        for (int j = 0; j < 4; ++j) acc[i][j] = f32x4{0.f, 0.f, 0.f, 0.f};

    const int nt = K >> 5;                    // K-tiles of 32

    if constexpr (DEPTH == 2) {
        // ---- R12 schedule: dbuf, stage t+1 at top, vmcnt(0) at end
        stage_a(0, 0); stage_b(0, 0);
        asm volatile("s_waitcnt vmcnt(0)" ::: "memory");
        __builtin_amdgcn_s_barrier();
        __builtin_amdgcn_sched_barrier(0);

        for (int t = 0; t < nt; ++t) {
            const int cur = t & 1, nb = cur ^ 1;
            const unsigned short* as = &As[cur][0];
            const unsigned short* bs = &Bs[cur][0];
            const bool pf = (t + 1 < nt);

            if (pf) { stage_a(t + 1, nb); stage_b(t + 1, nb); }

            s16x8 a8[8], b4[4];
#pragma unroll
            for (int i = 0; i < 4; ++i) a8[i] = *(const s16x8*)&as[aidx + i * 512];
#pragma unroll
            for (int j = 0; j < 4; ++j) b4[j] = *(const s16x8*)&bs[bidx + j * 512];
#pragma unroll
            for (int i = 0; i < 4; ++i) a8[4 + i] = *(const s16x8*)&as[aidx + (i + 4) * 512];

            __builtin_amdgcn_s_setprio(1);
#pragma unroll
            for (int i = 0; i < 8; ++i)
#pragma unroll
                for (int j = 0; j < 4; ++j)
                    acc[i][j] = mma<FP16>(a8[i], b4[j], acc[i][j]);
            __builtin_amdgcn_s_setprio(0);

            if (pf) { asm volatile("s_waitcnt vmcnt(0)" ::: "memory"); }
            __builtin_amdgcn_s_barrier();
            __builtin_amdgcn_sched_barrier(0);
        }
    } else {
        // ---- R14 schedule: 3-buf, stage t+2 at top, counted vmcnt(4)
        stage_a(0, 0); stage_b(0, 0);
        stage_a(1, 1); stage_b(1, 1);
        asm volatile("s_waitcnt vmcnt(4)" ::: "memory");
        __builtin_amdgcn_s_barrier();
        __builtin_amdgcn_sched_barrier(0);

        int cur = 0;
        for (int t = 0; t < nt; ++t) {
            const unsigned short* as = &As[cur][0];
            const unsigned short* bs = &Bs[cur][0];
            const bool pf2 = (t + 2 < nt);

            if (pf2) {
                const int nb = (cur >= 1) ? cur - 1 : 2;     // (t+2)%3
                stage_a(t + 2, nb); stage_b(t + 2, nb);
            }

            s16x8 a8[8], b4[4];
#pragma unroll
            for (int i = 0; i < 4; ++i) a8[i] = *(const s16x8*)&as[aidx + i * 512];
#pragma unroll
            for (int j = 0; j < 4; ++j) b4[j] = *(const s16x8*)&bs[bidx + j * 512];
#pragma unroll
            for (int i = 0; i < 4; ++i) a8[4 + i] = *(const s16x8*)&as[aidx + (i + 4) * 512];

            __builtin_amdgcn_s_setprio(1);
#pragma unroll
            for (int i = 0; i < 8; ++i)
#pragma unroll
                for (int j = 0; j < 4; ++j)
                    acc[i][j] = mma<FP16>(a8[i], b4[j], acc[i][j]);
            __builtin_amdgcn_s_setprio(0);

            if (pf2)               { asm volatile("s_waitcnt vmcnt(4)" ::: "memory"); }
            else if (t + 1 < nt)   { asm volatile("s_waitcnt vmcnt(0)" ::: "memory"); }
            __builtin_amdgcn_s_barrier();
            __builtin_amdgcn_sched_barrier(0);
            cur = (cur == 2) ? 0 : cur + 1;
        }
    }

    // ---- epilogue: C/D map col=lane&15, row=(lane>>4)*4+reg
    const int r0 = (lane >> 4) * 4;
    const long long rowbase = m0 + wr * 128 + r0;
    const long long colbase = n0 + wc * 64 + ml;
    if (MODE == 5) {
        // dual-output QKV: cols<1536 -> fp16 qk (ldc 1536); else bf16 v (ldc 768)
        const bool qkpart = (n0 < 1536);
#pragma unroll
        for (int i = 0; i < 8; ++i) {
            const long long rowb = rowbase + i * 16;
#pragma unroll
            for (int j = 0; j < 4; ++j) {
                const long long col = colbase + j * 16;
                const float bj = bias[col];
#pragma unroll
                for (int q = 0; q < 4; ++q) {
                    const float vv = acc[i][j][q] + bj;
                    if (qkpart) Ch [(rowb + q) * 1536LL + col]          = f2h(vv);
                    else        Ch2[(rowb + q) *  768LL + (col - 1536)] = f2bf(vv);
                }
            }
        }
    } else if (MODE == 3) {
        Ch += (long long)bz * sC;
        float* rs = rsum + (long long)bz * sR;
#pragma unroll
        for (int i = 0; i < 8; ++i) {
            const long long rowb = rowbase + i * 16;
            float srow0 = 0.f, srow1 = 0.f, srow2 = 0.f, srow3 = 0.f;
#pragma unroll
            for (int j = 0; j < 4; ++j) {
                const long long col = colbase + j * 16;
                {
                    const unsigned short u0 = f2bf(__expf(acc[i][j][0]));
                    const unsigned short u1 = f2bf(__expf(acc[i][j][1]));
                    const unsigned short u2 = f2bf(__expf(acc[i][j][2]));
                    const unsigned short u3 = f2bf(__expf(acc[i][j][3]));
                    Ch[(rowb + 0) * (long long)ldc + col] = u0;
                    Ch[(rowb + 1) * (long long)ldc + col] = u1;
                    Ch[(rowb + 2) * (long long)ldc + col] = u2;
                    Ch[(rowb + 3) * (long long)ldc + col] = u3;
                    srow0 += bf2f(u0); srow1 += bf2f(u1);
                    srow2 += bf2f(u2); srow3 += bf2f(u3);
                }
            }
            // reduce the wave's 64-col partial across the 16-lane col group
#pragma unroll
            for (int o = 1; o < 16; o <<= 1) {
                srow0 += __shfl_xor(srow0, o);
                srow1 += __shfl_xor(srow1, o);
                srow2 += __shfl_xor(srow2, o);
                srow3 += __shfl_xor(srow3, o);
            }
            if (ml == 0) {
                atomicAdd(&rs[rowb + 0], srow0);
                atomicAdd(&rs[rowb + 1], srow1);
                atomicAdd(&rs[rowb + 2], srow2);
                atomicAdd(&rs[rowb + 3], srow3);
            }
        }
    } else {   // MODE 4
        Cf += (long long)bz * sC;
        rvec += (long long)bz * sR;
#pragma unroll
        for (int i = 0; i < 8; ++i) {
            const long long rowb = rowbase + i * 16;
            float inv0 = 1.0f / rvec[rowb + 0];
            float inv1 = 1.0f / rvec[rowb + 1];
            float inv2 = 1.0f / rvec[rowb + 2];
            float inv3 = 1.0f / rvec[rowb + 3];
#pragma unroll
            for (int j = 0; j < 4; ++j) {
                const long long col = colbase + j * 16;
                Cf[(rowb + 0) * (long long)ldc + col] = acc[i][j][0] * inv0;
                Cf[(rowb + 1) * (long long)ldc + col] = acc[i][j][1] * inv1;
                Cf[(rowb + 2) * (long long)ldc + col] = acc[i][j][2] * inv2;
                Cf[(rowb + 3) * (long long)ldc + col] = acc[i][j][3] * inv3;
            }
        }
    }
}

// f32 -> fp16 convert, 4 elems/thread, two source buffers in one launch
__global__ __launch_bounds__(256)
void cvt_f16_2(const float* __restrict__ a, long long na4,
               const float* __restrict__ b, long long nb4,
               unsigned short* __restrict__ oa, unsigned short* __restrict__ ob)
{
    const long long i = (long long)blockIdx.x * 256 + threadIdx.x;
    const float4* src;
    h16x4* dst;
    long long idx;
    if (i < na4)            { src = (const float4*)a; dst = (h16x4*)oa; idx = i; }
    else if (i < na4 + nb4) { src = (const float4*)b; dst = (h16x4*)ob; idx = i - na4; }
    else return;
    const float4 v = src[idx];
    h16x4 o;
    o.x = (_Float16)v.x; o.y = (_Float16)v.y;
    o.z = (_Float16)v.z; o.w = (_Float16)v.w;
    dst[idx] = o;
}

// vt[b][h][n] = v[b*2048+n][h]   (V transpose, bf16)
__global__ __launch_bounds__(256)
void transpose_v(const unsigned short* __restrict__ v, unsigned short* __restrict__ vt)
{
    __shared__ unsigned short t[32][33];
    const int b = blockIdx.z;
    const int n0 = blockIdx.x * 32, h0 = blockIdx.y * 32;
    const int tx = threadIdx.x, ty = threadIdx.y;      // 32 x 8
    const unsigned short* src = v + (long long)b * 2048 * 768;
#pragma unroll
    for (int q = 0; q < 4; ++q)
        t[ty + q * 8][tx] = src[(long long)(n0 + ty + q * 8) * 768 + h0 + tx];
    __syncthreads();
    unsigned short* dst = vt + ((long long)b * 768 + h0) * 2048 + n0;
#pragma unroll
    for (int q = 0; q < 4; ++q)
        dst[(long long)(ty + q * 8) * 2048 + tx] = t[tx][ty + q * 8];
}

extern "C" void kernel_launch(void* const* d_in, const int* in_sizes, int n_in,
                              void* d_out, int out_size, void* d_ws, size_t ws_size,
                              hipStream_t stream)
{
    const float* x    = (const float*)d_in[0];   // [16384, 768]
    const float* W    = (const float*)d_in[1];   // [2304, 768]
    const float* bias = (const float*)d_in[2];   // [2304]
    float* out = (float*)d_out;                  // [8, 2048, 768]

    // ---- workspace layout (bytes), total 196.5 MB
    char* ws = (char*)d_ws;
    unsigned short* xh = (unsigned short*)ws;                      // [16384,768] fp16
    unsigned short* Wh = (unsigned short*)(ws + 25165824LL);       // [2304,768] fp16
    unsigned short* qk = (unsigned short*)(ws + 28704768LL);       // [16384,1536] fp16
    unsigned short* v  = (unsigned short*)(ws + 79036416LL);       // [16384,768] bf16
    unsigned short* vt = (unsigned short*)(ws + 104202240LL);      // [8,768,2048] bf16
    unsigned short* E  = (unsigned short*)(ws + 129368064LL);      // [8,2048,2048] bf16
    float*          r  = (float*)(ws + 196476928LL);               // [16384] f32

    // C1+C2: convert x and W to fp16 in one launch
    cvt_f16_2<<<dim3(14016), dim3(256), 0, stream>>>(
        x, 3145728LL, W, 442368LL, xh, Wh);

    // zero row-sum accumulator (K2 atomically accumulates into it)
    hipMemsetAsync(r, 0, 16384 * sizeof(float), stream);

    // K1: qkv = x @ W^T + b  (fp16, M=16384 N=2304 K=768), merged dual-output
    gemm_mfma<5, true, 2, 3><<<dim3(9, 64, 1), dim3(512), 0, stream>>>(
        xh, Wh, bias, nullptr, nullptr, nullptr, qk, v,
        768, 768, 768, 0, 0, 0, 0, 0);

    // T: vt = v^T per batch
    transpose_v<<<dim3(64, 24, 8), dim3(32, 8), 0, stream>>>(v, vt);

    // K2: E = exp(q @ k^T), fused row-sum -> r  (fp16 in, M=N=2048 K=768, z=8)
    gemm_mfma<3, true, 1, 2><<<dim3(8, 8, 8), dim3(512), 0, stream>>>(
        qk, qk + 768, nullptr, nullptr, r, nullptr, E, nullptr,
        768, 1536, 1536, 2048,
        2048LL * 1536, 2048LL * 1536, 2048LL * 2048, 2048);

    // K4: out = (E @ vt^T) * (1/r[row])  (bf16, M=2048 N=768 K=2048, z=8)
    gemm_mfma<4, false, 1, 3><<<dim3(3, 8, 8), dim3(512), 0, stream>>>(
        E, vt, nullptr, r, nullptr, out, nullptr, nullptr,
        2048, 2048, 2048, 768,
        2048LL * 2048, 768LL * 2048, 2048LL * 768, 2048);
}

// Round 9
// 328.376 us; speedup vs baseline: 1.0520x; 1.0520x over previous
//
#include <hip/hip_runtime.h>

// ---------------------------------------------------------------------------
// Attention_4956392259713 — round 16: unbundle R15 — revert QKV merge, keep
// per-kernel DEPTH + fused rowsum.
// qkv = x@W^T+b; S = q@k^T (unscaled); P = softmax(S); out = P@v
//
// R15 post-mortem: merged QKV = 129us @ 18% MfmaUtil vs split 69+35=104
// (3 block-waves, last 25% full + dual-stride epilogue) -> revert merge.
// K2-DEPTH2 + fused rowsum + K4 1/r were UNMEASURED (hidden under QKV
// replays in top-5) -> keep them, this round isolates their effect.
//  - K1a: MODE 1 fp16 out, grid 6x64, DEPTH3/SWZ2   (R14-best: ~69us)
//  - K1b: MODE 2 bf16 out, grid 3x64, DEPTH3/SWZ2   (R14-best: ~35us)
//  - K2:  MODE 3 exp->bf16 + fused row-sum atomics, DEPTH2/SWZ1 (R12-best
//         schedule ~69us; epilogue adds shfl-tree + 4 atomicAdd/wave/i)
//  - K4:  MODE 4 * (1/r[row]), DEPTH3/SWZ1 (identical math to old
//         rowsum_recip path: same 1/sum division, same multiply)
//  - no rowsum kernel (-1 launch, -67MB E re-read); r zeroed by memset
// Core loops/swizzle unchanged (0 bank conflicts since R9).
// Swizzle (64B rows): 16B-unit U=u^((row>>1)&3); write = linear gld16 dest +
// pre-swizzled GLOBAL column (rule #21); read folded into per-lane ku.
// Numerics: fp16 QKV/QK^T; bf16 E and PV; no max subtraction (logits ~55).
// Fragment maps (m89-verified): A/B idx=lane&15, k=(lane>>4)*8+j;
//                               C/D col=lane&15, row=(lane>>4)*4+reg.
// ---------------------------------------------------------------------------

typedef short    s16x8 __attribute__((ext_vector_type(8)));
typedef _Float16 h16x8 __attribute__((ext_vector_type(8)));
typedef _Float16 h16x4 __attribute__((ext_vector_type(4)));
typedef float    f32x4 __attribute__((ext_vector_type(4)));

__device__ __forceinline__ unsigned short f2bf(float x) {
    unsigned u = __float_as_uint(x);
    u += 0x7fffu + ((u >> 16) & 1u);          // RTNE
    return (unsigned short)(u >> 16);
}
__device__ __forceinline__ float bf2f(unsigned short h) {
    return __uint_as_float(((unsigned)h) << 16);
}
__device__ __forceinline__ unsigned short f2h(float x) {
    _Float16 h = (_Float16)x;                 // v_cvt_f16_f32, RTNE
    unsigned short u;
    __builtin_memcpy(&u, &h, 2);
    return u;
}
__device__ __forceinline__ h16x8 as_h(s16x8 v) {
    h16x8 r; __builtin_memcpy(&r, &v, 16); return r;
}

// async global->LDS, 16 B per lane; LDS dest = wave-uniform base + lane*16
__device__ __forceinline__ void gld16(const void* g, void* l) {
    __builtin_amdgcn_global_load_lds(
        (const __attribute__((address_space(1))) unsigned int*)(unsigned long long)g,
        (__attribute__((address_space(3))) unsigned int*)(unsigned)(unsigned long long)l,
        16, 0, 0);
}

template<bool FP16>
__device__ __forceinline__ f32x4 mma(s16x8 a, s16x8 b, f32x4 c) {
    if constexpr (FP16)
        return __builtin_amdgcn_mfma_f32_16x16x32_f16(as_h(a), as_h(b), c, 0, 0, 0);
    else
        return __builtin_amdgcn_mfma_f32_16x16x32_bf16(a, b, c, 0, 0, 0);
}

// NT GEMM, 512 thr = 8 waves (2Mx4N), tile 256x256, BK=32.
// MODE 1: C = acc + bias -> fp16                       [K1a]
// MODE 2: C = acc + bias -> bf16                       [K1b]
// MODE 3: C = exp(acc) -> bf16, fused row-sum atomics  [K2]
// MODE 4: C = acc * (1/rvec[row]) -> f32               [K4]
// SWZ 1: 3D batch-per-XCD; 2: 2D row-chunk-per-XCD (gridDim.y%8==0)
// DEPTH 2: dbuf, stage t+1 @top, vmcnt(0) @end (R12 schedule)
// DEPTH 3: 3-buf, stage t+2 @top, vmcnt(4) @end — counted, never 0 (R14)
template<int MODE, bool FP16, int SWZ, int DEPTH>
__global__ __launch_bounds__(512, 2)
void gemm_mfma(const unsigned short* __restrict__ A, const unsigned short* __restrict__ B,
               const float* __restrict__ bias, const float* __restrict__ rvec,
               float* __restrict__ rsum,
               float* __restrict__ Cf, unsigned short* __restrict__ Ch,
               int K, int lda, int ldb, int ldc,
               long long sA, long long sB, long long sC, long long sR)
{
    __shared__ unsigned short As[DEPTH][8192];   // [256 rows][32 k] 2B, swizzled
    __shared__ unsigned short Bs[DEPTH][8192];

    int bx = blockIdx.x, by = blockIdx.y, bz = blockIdx.z;
    if (SWZ == 1) {
        const int l = bx + gridDim.x * (by + gridDim.y * bz);
        bz = l & 7;
        const int t = l >> 3;
        bx = t % gridDim.x;
        by = t / gridDim.x;
    } else if (SWZ == 2) {
        const int l = bx + gridDim.x * by;
        const int c = l & 7;
        const int t = l >> 3;
        const int rows = gridDim.y >> 3;
        bx = t % gridDim.x;
        by = c * rows + t / gridDim.x;
    }

    A += (long long)bz * sA;
    B += (long long)bz * sB;

    const long long m0 = (long long)by * 256;
    const long long n0 = (long long)bx * 256;

    const int tid  = threadIdx.x;
    const int wave = tid >> 6, lane = tid & 63;
    const int wr = wave >> 2, wc = wave & 3;             // 2M x 4N wave grid
    const int ml = lane & 15;                            // fragment row-in-16
    // swizzled k-unit for fragment reads: U = u ^ ((row>>1)&3)
    const int ku = (((lane >> 4) ^ ((ml >> 1) & 3)) * 8);
    const int srr = wave * 16 + (lane >> 2);             // staging row 0..127
    // pre-swizzled GLOBAL column (write side; gld16 LDS dest stays linear)
    const int skc = (((lane & 3) ^ ((lane >> 3) & 3)) * 8);

    const int aidx = (wr * 128 + ml) * 32 + ku;          // LDS elem index
    const int bidx = (wc * 64  + ml) * 32 + ku;

    const unsigned short* Abase = A + (m0 + srr) * (long long)lda + skc;
    const unsigned short* Bbase = B + (n0 + srr) * (long long)ldb + skc;
    const long long a128 = 128LL * lda, b128 = 128LL * ldb;

    auto stage_a = [&](int t, int buf) {
        const unsigned short* p = Abase + t * 32;
        gld16(p,        &As[buf][wave * 512]);
        gld16(p + a128, &As[buf][4096 + wave * 512]);
    };
    auto stage_b = [&](int t, int buf) {
        const unsigned short* p = Bbase + t * 32;
        gld16(p,        &Bs[buf][wave * 512]);
        gld16(p + b128, &Bs[buf][4096 + wave * 512]);
    };

    f32x4 acc[8][4];
#pragma unroll
    for (int i = 0; i < 8; ++i)
#pragma unroll
        for (int j = 0; j < 4; ++j) acc[i][j] = f32x4{0.f, 0.f, 0.f, 0.f};

    const int nt = K >> 5;                    // K-tiles of 32

    if constexpr (DEPTH == 2) {
        // ---- R12 schedule: dbuf, stage t+1 at top, vmcnt(0) at end
        stage_a(0, 0); stage_b(0, 0);
        asm volatile("s_waitcnt vmcnt(0)" ::: "memory");
        __builtin_amdgcn_s_barrier();
        __builtin_amdgcn_sched_barrier(0);

        for (int t = 0; t < nt; ++t) {
            const int cur = t & 1, nb = cur ^ 1;
            const unsigned short* as = &As[cur][0];
            const unsigned short* bs = &Bs[cur][0];
            const bool pf = (t + 1 < nt);

            if (pf) { stage_a(t + 1, nb); stage_b(t + 1, nb); }

            s16x8 a8[8], b4[4];
#pragma unroll
            for (int i = 0; i < 4; ++i) a8[i] = *(const s16x8*)&as[aidx + i * 512];
#pragma unroll
            for (int j = 0; j < 4; ++j) b4[j] = *(const s16x8*)&bs[bidx + j * 512];
#pragma unroll
            for (int i = 0; i < 4; ++i) a8[4 + i] = *(const s16x8*)&as[aidx + (i + 4) * 512];

            __builtin_amdgcn_s_setprio(1);
#pragma unroll
            for (int i = 0; i < 8; ++i)
#pragma unroll
                for (int j = 0; j < 4; ++j)
                    acc[i][j] = mma<FP16>(a8[i], b4[j], acc[i][j]);
            __builtin_amdgcn_s_setprio(0);

            if (pf) { asm volatile("s_waitcnt vmcnt(0)" ::: "memory"); }
            __builtin_amdgcn_s_barrier();
            __builtin_amdgcn_sched_barrier(0);
        }
    } else {
        // ---- R14 schedule: 3-buf, stage t+2 at top, counted vmcnt(4)
        stage_a(0, 0); stage_b(0, 0);
        stage_a(1, 1); stage_b(1, 1);
        asm volatile("s_waitcnt vmcnt(4)" ::: "memory");
        __builtin_amdgcn_s_barrier();
        __builtin_amdgcn_sched_barrier(0);

        int cur = 0;
        for (int t = 0; t < nt; ++t) {
            const unsigned short* as = &As[cur][0];
            const unsigned short* bs = &Bs[cur][0];
            const bool pf2 = (t + 2 < nt);

            if (pf2) {
                const int nb = (cur >= 1) ? cur - 1 : 2;     // (t+2)%3
                stage_a(t + 2, nb); stage_b(t + 2, nb);
            }

            s16x8 a8[8], b4[4];
#pragma unroll
            for (int i = 0; i < 4; ++i) a8[i] = *(const s16x8*)&as[aidx + i * 512];
#pragma unroll
            for (int j = 0; j < 4; ++j) b4[j] = *(const s16x8*)&bs[bidx + j * 512];
#pragma unroll
            for (int i = 0; i < 4; ++i) a8[4 + i] = *(const s16x8*)&as[aidx + (i + 4) * 512];

            __builtin_amdgcn_s_setprio(1);
#pragma unroll
            for (int i = 0; i < 8; ++i)
#pragma unroll
                for (int j = 0; j < 4; ++j)
                    acc[i][j] = mma<FP16>(a8[i], b4[j], acc[i][j]);
            __builtin_amdgcn_s_setprio(0);

            if (pf2)               { asm volatile("s_waitcnt vmcnt(4)" ::: "memory"); }
            else if (t + 1 < nt)   { asm volatile("s_waitcnt vmcnt(0)" ::: "memory"); }
            __builtin_amdgcn_s_barrier();
            __builtin_amdgcn_sched_barrier(0);
            cur = (cur == 2) ? 0 : cur + 1;
        }
    }

    // ---- epilogue: C/D map col=lane&15, row=(lane>>4)*4+reg
    const int r0 = (lane >> 4) * 4;
    const long long rowbase = m0 + wr * 128 + r0;
    const long long colbase = n0 + wc * 64 + ml;
    if (MODE == 1 || MODE == 2) {
#pragma unroll
        for (int i = 0; i < 8; ++i) {
            const long long rowb = rowbase + i * 16;
#pragma unroll
            for (int j = 0; j < 4; ++j) {
                const long long col = colbase + j * 16;
                const float bj = bias[col];
#pragma unroll
                for (int q = 0; q < 4; ++q) {
                    const float vv = acc[i][j][q] + bj;
                    Ch[(rowb + q) * (long long)ldc + col] = (MODE == 1) ? f2h(vv) : f2bf(vv);
                }
            }
        }
    } else if (MODE == 3) {
        Ch += (long long)bz * sC;
        float* rs = rsum + (long long)bz * sR;
#pragma unroll
        for (int i = 0; i < 8; ++i) {
            const long long rowb = rowbase + i * 16;
            float srow0 = 0.f, srow1 = 0.f, srow2 = 0.f, srow3 = 0.f;
#pragma unroll
            for (int j = 0; j < 4; ++j) {
                const long long col = colbase + j * 16;
                const unsigned short u0 = f2bf(__expf(acc[i][j][0]));
                const unsigned short u1 = f2bf(__expf(acc[i][j][1]));
                const unsigned short u2 = f2bf(__expf(acc[i][j][2]));
                const unsigned short u3 = f2bf(__expf(acc[i][j][3]));
                Ch[(rowb + 0) * (long long)ldc + col] = u0;
                Ch[(rowb + 1) * (long long)ldc + col] = u1;
                Ch[(rowb + 2) * (long long)ldc + col] = u2;
                Ch[(rowb + 3) * (long long)ldc + col] = u3;
                srow0 += bf2f(u0); srow1 += bf2f(u1);
                srow2 += bf2f(u2); srow3 += bf2f(u3);
            }
            // reduce the wave's 64-col partial across the 16-lane col group
#pragma unroll
            for (int o = 1; o < 16; o <<= 1) {
                srow0 += __shfl_xor(srow0, o);
                srow1 += __shfl_xor(srow1, o);
                srow2 += __shfl_xor(srow2, o);
                srow3 += __shfl_xor(srow3, o);
            }
            if (ml == 0) {
                atomicAdd(&rs[rowb + 0], srow0);
                atomicAdd(&rs[rowb + 1], srow1);
                atomicAdd(&rs[rowb + 2], srow2);
                atomicAdd(&rs[rowb + 3], srow3);
            }
        }
    } else {   // MODE 4
        Cf += (long long)bz * sC;
        rvec += (long long)bz * sR;
#pragma unroll
        for (int i = 0; i < 8; ++i) {
            const long long rowb = rowbase + i * 16;
            const float inv0 = 1.0f / rvec[rowb + 0];
            const float inv1 = 1.0f / rvec[rowb + 1];
            const float inv2 = 1.0f / rvec[rowb + 2];
            const float inv3 = 1.0f / rvec[rowb + 3];
#pragma unroll
            for (int j = 0; j < 4; ++j) {
                const long long col = colbase + j * 16;
                Cf[(rowb + 0) * (long long)ldc + col] = acc[i][j][0] * inv0;
                Cf[(rowb + 1) * (long long)ldc + col] = acc[i][j][1] * inv1;
                Cf[(rowb + 2) * (long long)ldc + col] = acc[i][j][2] * inv2;
                Cf[(rowb + 3) * (long long)ldc + col] = acc[i][j][3] * inv3;
            }
        }
    }
}

// f32 -> fp16 convert, 4 elems/thread, two source buffers in one launch
__global__ __launch_bounds__(256)
void cvt_f16_2(const float* __restrict__ a, long long na4,
               const float* __restrict__ b, long long nb4,
               unsigned short* __restrict__ oa, unsigned short* __restrict__ ob)
{
    const long long i = (long long)blockIdx.x * 256 + threadIdx.x;
    const float4* src;
    h16x4* dst;
    long long idx;
    if (i < na4)            { src = (const float4*)a; dst = (h16x4*)oa; idx = i; }
    else if (i < na4 + nb4) { src = (const float4*)b; dst = (h16x4*)ob; idx = i - na4; }
    else return;
    const float4 v = src[idx];
    h16x4 o;
    o.x = (_Float16)v.x; o.y = (_Float16)v.y;
    o.z = (_Float16)v.z; o.w = (_Float16)v.w;
    dst[idx] = o;
}

// vt[b][h][n] = v[b*2048+n][h]   (V transpose, bf16)
__global__ __launch_bounds__(256)
void transpose_v(const unsigned short* __restrict__ v, unsigned short* __restrict__ vt)
{
    __shared__ unsigned short t[32][33];
    const int b = blockIdx.z;
    const int n0 = blockIdx.x * 32, h0 = blockIdx.y * 32;
    const int tx = threadIdx.x, ty = threadIdx.y;      // 32 x 8
    const unsigned short* src = v + (long long)b * 2048 * 768;
#pragma unroll
    for (int q = 0; q < 4; ++q)
        t[ty + q * 8][tx] = src[(long long)(n0 + ty + q * 8) * 768 + h0 + tx];
    __syncthreads();
    unsigned short* dst = vt + ((long long)b * 768 + h0) * 2048 + n0;
#pragma unroll
    for (int q = 0; q < 4; ++q)
        dst[(long long)(ty + q * 8) * 2048 + tx] = t[tx][ty + q * 8];
}

extern "C" void kernel_launch(void* const* d_in, const int* in_sizes, int n_in,
                              void* d_out, int out_size, void* d_ws, size_t ws_size,
                              hipStream_t stream)
{
    const float* x    = (const float*)d_in[0];   // [16384, 768]
    const float* W    = (const float*)d_in[1];   // [2304, 768]
    const float* bias = (const float*)d_in[2];   // [2304]
    float* out = (float*)d_out;                  // [8, 2048, 768]

    // ---- workspace layout (bytes), total 196.5 MB
    char* ws = (char*)d_ws;
    unsigned short* xh = (unsigned short*)ws;                      // [16384,768] fp16
    unsigned short* Wh = (unsigned short*)(ws + 25165824LL);       // [2304,768] fp16
    unsigned short* qk = (unsigned short*)(ws + 28704768LL);       // [16384,1536] fp16
    unsigned short* v  = (unsigned short*)(ws + 79036416LL);       // [16384,768] bf16
    unsigned short* vt = (unsigned short*)(ws + 104202240LL);      // [8,768,2048] bf16
    unsigned short* E  = (unsigned short*)(ws + 129368064LL);      // [8,2048,2048] bf16
    float*          r  = (float*)(ws + 196476928LL);               // [16384] f32

    // C1+C2: convert x and W to fp16 in one launch
    cvt_f16_2<<<dim3(14016), dim3(256), 0, stream>>>(
        x, 3145728LL, W, 442368LL, xh, Wh);

    // zero row-sum accumulator (K2 atomically accumulates into it)
    hipMemsetAsync(r, 0, 16384 * sizeof(float), stream);

    // K1a: qk = x @ Wqk^T + b  (fp16, M=16384 N=1536 K=768), 2D chunk swizzle
    gemm_mfma<1, true, 2, 3><<<dim3(6, 64, 1), dim3(512), 0, stream>>>(
        xh, Wh, bias, nullptr, nullptr, nullptr, qk,
        768, 768, 768, 1536, 0, 0, 0, 0);

    // K1b: v = x @ Wv^T + b -> bf16  (M=16384 N=768 K=768), 2D chunk swizzle
    gemm_mfma<2, true, 2, 3><<<dim3(3, 64, 1), dim3(512), 0, stream>>>(
        xh, Wh + 1536LL * 768, bias + 1536, nullptr, nullptr, nullptr, v,
        768, 768, 768, 768, 0, 0, 0, 0);

    // T: vt = v^T per batch
    transpose_v<<<dim3(64, 24, 8), dim3(32, 8), 0, stream>>>(v, vt);

    // K2: E = exp(q @ k^T), fused row-sum -> r  (fp16 in, M=N=2048 K=768, z=8)
    gemm_mfma<3, true, 1, 2><<<dim3(8, 8, 8), dim3(512), 0, stream>>>(
        qk, qk + 768, nullptr, nullptr, r, nullptr, E,
        768, 1536, 1536, 2048,
        2048LL * 1536, 2048LL * 1536, 2048LL * 2048, 2048);

    // K4: out = (E @ vt^T) * (1/r[row])  (bf16, M=2048 N=768 K=2048, z=8)
    gemm_mfma<4, false, 1, 3><<<dim3(3, 8, 8), dim3(512), 0, stream>>>(
        E, vt, nullptr, r, nullptr, out, nullptr,
        2048, 2048, 2048, 768,
        2048LL * 2048, 768LL * 2048, 2048LL * 768, 2048);
}

// Round 11
// 323.009 us; speedup vs baseline: 1.0695x; 1.0166x over previous
//
#include <hip/hip_runtime.h>

// ---------------------------------------------------------------------------
// Attention_4956392259713 — round 18: R17 recombination, compile fix.
// (R17 failed to compile: K4 call had out/nullptr swapped — float* passed to
// the Ch slot. Fixed argument order; kernel code otherwise identical.)
// qkv = x@W^T+b; S = q@k^T (unscaled); P = softmax(S); out = P@v
//
// Measured depth preferences (R12/R14/R16 isolation):
//   K2:  DEPTH2-plain 68.8us < DEPTH2+fused-atomics 78 < DEPTH3 80
//   K1a/K1b/K4: DEPTH3 better by ~29us combined (R14 vs R12)
// R16's atomic row-sum fusion = net negative: REVERTED.
// This round = R14 exactly, except K2 at DEPTH2 (its best):
//   - K1a: MODE 1 fp16 out, grid 6x64, DEPTH3/SWZ2
//   - K1b: MODE 2 bf16 out, grid 3x64, DEPTH3/SWZ2
//   - K2:  MODE 3 exp->bf16 plain, grid (8,8,8), DEPTH2/SWZ1
//   - rowsum_recip: r[row] = 1/sum(E[row]) (separate kernel, as R14)
//   - K4:  MODE 4 acc*rvec[row], grid (3,8,8), DEPTH3/SWZ1
// Core loops/swizzle unchanged (0 bank conflicts since R9; VGPR 100).
// Swizzle (64B rows): 16B-unit U=u^((row>>1)&3); write = linear gld16 dest +
// pre-swizzled GLOBAL column (rule #21); read folded into per-lane ku.
// Numerics: fp16 QKV/QK^T; bf16 E and PV; no max subtraction (logits ~55).
// Fragment maps (m89-verified): A/B idx=lane&15, k=(lane>>4)*8+j;
//                               C/D col=lane&15, row=(lane>>4)*4+reg.
// ---------------------------------------------------------------------------

typedef short    s16x8 __attribute__((ext_vector_type(8)));
typedef _Float16 h16x8 __attribute__((ext_vector_type(8)));
typedef _Float16 h16x4 __attribute__((ext_vector_type(4)));
typedef float    f32x4 __attribute__((ext_vector_type(4)));

__device__ __forceinline__ unsigned short f2bf(float x) {
    unsigned u = __float_as_uint(x);
    u += 0x7fffu + ((u >> 16) & 1u);          // RTNE
    return (unsigned short)(u >> 16);
}
__device__ __forceinline__ float bf2f(unsigned short h) {
    return __uint_as_float(((unsigned)h) << 16);
}
__device__ __forceinline__ unsigned short f2h(float x) {
    _Float16 h = (_Float16)x;                 // v_cvt_f16_f32, RTNE
    unsigned short u;
    __builtin_memcpy(&u, &h, 2);
    return u;
}
__device__ __forceinline__ h16x8 as_h(s16x8 v) {
    h16x8 r; __builtin_memcpy(&r, &v, 16); return r;
}

// async global->LDS, 16 B per lane; LDS dest = wave-uniform base + lane*16
__device__ __forceinline__ void gld16(const void* g, void* l) {
    __builtin_amdgcn_global_load_lds(
        (const __attribute__((address_space(1))) unsigned int*)(unsigned long long)g,
        (__attribute__((address_space(3))) unsigned int*)(unsigned)(unsigned long long)l,
        16, 0, 0);
}

template<bool FP16>
__device__ __forceinline__ f32x4 mma(s16x8 a, s16x8 b, f32x4 c) {
    if constexpr (FP16)
        return __builtin_amdgcn_mfma_f32_16x16x32_f16(as_h(a), as_h(b), c, 0, 0, 0);
    else
        return __builtin_amdgcn_mfma_f32_16x16x32_bf16(a, b, c, 0, 0, 0);
}

// NT GEMM, 512 thr = 8 waves (2Mx4N), tile 256x256, BK=32.
// MODE 1: C = acc + bias -> fp16        [K1a]
// MODE 2: C = acc + bias -> bf16        [K1b]
// MODE 3: C = exp(acc)   -> bf16        [K2]
// MODE 4: C = acc * rvec[row] -> f32    [K4]  (rvec = 1/rowsum)
// SWZ 1: 3D batch-per-XCD; 2: 2D row-chunk-per-XCD (gridDim.y%8==0)
// DEPTH 2: dbuf, stage t+1 @top, vmcnt(0) @end (R12 schedule)
// DEPTH 3: 3-buf, stage t+2 @top, vmcnt(4) @end — counted, never 0 (R14)
template<int MODE, bool FP16, int SWZ, int DEPTH>
__global__ __launch_bounds__(512, 2)
void gemm_mfma(const unsigned short* __restrict__ A, const unsigned short* __restrict__ B,
               const float* __restrict__ bias, const float* __restrict__ rvec,
               float* __restrict__ Cf, unsigned short* __restrict__ Ch,
               int K, int lda, int ldb, int ldc,
               long long sA, long long sB, long long sC, long long sR)
{
    __shared__ unsigned short As[DEPTH][8192];   // [256 rows][32 k] 2B, swizzled
    __shared__ unsigned short Bs[DEPTH][8192];

    int bx = blockIdx.x, by = blockIdx.y, bz = blockIdx.z;
    if (SWZ == 1) {
        const int l = bx + gridDim.x * (by + gridDim.y * bz);
        bz = l & 7;
        const int t = l >> 3;
        bx = t % gridDim.x;
        by = t / gridDim.x;
    } else if (SWZ == 2) {
        const int l = bx + gridDim.x * by;
        const int c = l & 7;
        const int t = l >> 3;
        const int rows = gridDim.y >> 3;
        bx = t % gridDim.x;
        by = c * rows + t / gridDim.x;
    }

    A += (long long)bz * sA;
    B += (long long)bz * sB;

    const long long m0 = (long long)by * 256;
    const long long n0 = (long long)bx * 256;

    const int tid  = threadIdx.x;
    const int wave = tid >> 6, lane = tid & 63;
    const int wr = wave >> 2, wc = wave & 3;             // 2M x 4N wave grid
    const int ml = lane & 15;                            // fragment row-in-16
    // swizzled k-unit for fragment reads: U = u ^ ((row>>1)&3)
    const int ku = (((lane >> 4) ^ ((ml >> 1) & 3)) * 8);
    const int srr = wave * 16 + (lane >> 2);             // staging row 0..127
    // pre-swizzled GLOBAL column (write side; gld16 LDS dest stays linear)
    const int skc = (((lane & 3) ^ ((lane >> 3) & 3)) * 8);

    const int aidx = (wr * 128 + ml) * 32 + ku;          // LDS elem index
    const int bidx = (wc * 64  + ml) * 32 + ku;

    const unsigned short* Abase = A + (m0 + srr) * (long long)lda + skc;
    const unsigned short* Bbase = B + (n0 + srr) * (long long)ldb + skc;
    const long long a128 = 128LL * lda, b128 = 128LL * ldb;

    auto stage_a = [&](int t, int buf) {
        const unsigned short* p = Abase + t * 32;
        gld16(p,        &As[buf][wave * 512]);
        gld16(p + a128, &As[buf][4096 + wave * 512]);
    };
    auto stage_b = [&](int t, int buf) {
        const unsigned short* p = Bbase + t * 32;
        gld16(p,        &Bs[buf][wave * 512]);
        gld16(p + b128, &Bs[buf][4096 + wave * 512]);
    };

    f32x4 acc[8][4];
#pragma unroll
    for (int i = 0; i < 8; ++i)
#pragma unroll
        for (int j = 0; j < 4; ++j) acc[i][j] = f32x4{0.f, 0.f, 0.f, 0.f};

    const int nt = K >> 5;                    // K-tiles of 32

    if constexpr (DEPTH == 2) {
        // ---- R12 schedule: dbuf, stage t+1 at top, vmcnt(0) at end
        stage_a(0, 0); stage_b(0, 0);
        asm volatile("s_waitcnt vmcnt(0)" ::: "memory");
        __builtin_amdgcn_s_barrier();
        __builtin_amdgcn_sched_barrier(0);

        for (int t = 0; t < nt; ++t) {
            const int cur = t & 1, nb = cur ^ 1;
            const unsigned short* as = &As[cur][0];
            const unsigned short* bs = &Bs[cur][0];
            const bool pf = (t + 1 < nt);

            if (pf) { stage_a(t + 1, nb); stage_b(t + 1, nb); }

            s16x8 a8[8], b4[4];
#pragma unroll
            for (int i = 0; i < 4; ++i) a8[i] = *(const s16x8*)&as[aidx + i * 512];
#pragma unroll
            for (int j = 0; j < 4; ++j) b4[j] = *(const s16x8*)&bs[bidx + j * 512];
#pragma unroll
            for (int i = 0; i < 4; ++i) a8[4 + i] = *(const s16x8*)&as[aidx + (i + 4) * 512];

            __builtin_amdgcn_s_setprio(1);
#pragma unroll
            for (int i = 0; i < 8; ++i)
#pragma unroll
                for (int j = 0; j < 4; ++j)
                    acc[i][j] = mma<FP16>(a8[i], b4[j], acc[i][j]);
            __builtin_amdgcn_s_setprio(0);

            if (pf) { asm volatile("s_waitcnt vmcnt(0)" ::: "memory"); }
            __builtin_amdgcn_s_barrier();
            __builtin_amdgcn_sched_barrier(0);
        }
    } else {
        // ---- R14 schedule: 3-buf, stage t+2 at top, counted vmcnt(4)
        stage_a(0, 0); stage_b(0, 0);
        stage_a(1, 1); stage_b(1, 1);
        asm volatile("s_waitcnt vmcnt(4)" ::: "memory");
        __builtin_amdgcn_s_barrier();
        __builtin_amdgcn_sched_barrier(0);

        int cur = 0;
        for (int t = 0; t < nt; ++t) {
            const unsigned short* as = &As[cur][0];
            const unsigned short* bs = &Bs[cur][0];
            const bool pf2 = (t + 2 < nt);

            if (pf2) {
                const int nb = (cur >= 1) ? cur - 1 : 2;     // (t+2)%3
                stage_a(t + 2, nb); stage_b(t + 2, nb);
            }

            s16x8 a8[8], b4[4];
#pragma unroll
            for (int i = 0; i < 4; ++i) a8[i] = *(const s16x8*)&as[aidx + i * 512];
#pragma unroll
            for (int j = 0; j < 4; ++j) b4[j] = *(const s16x8*)&bs[bidx + j * 512];
#pragma unroll
            for (int i = 0; i < 4; ++i) a8[4 + i] = *(const s16x8*)&as[aidx + (i + 4) * 512];

            __builtin_amdgcn_s_setprio(1);
#pragma unroll
            for (int i = 0; i < 8; ++i)
#pragma unroll
                for (int j = 0; j < 4; ++j)
                    acc[i][j] = mma<FP16>(a8[i], b4[j], acc[i][j]);
            __builtin_amdgcn_s_setprio(0);

            if (pf2)               { asm volatile("s_waitcnt vmcnt(4)" ::: "memory"); }
            else if (t + 1 < nt)   { asm volatile("s_waitcnt vmcnt(0)" ::: "memory"); }
            __builtin_amdgcn_s_barrier();
            __builtin_amdgcn_sched_barrier(0);
            cur = (cur == 2) ? 0 : cur + 1;
        }
    }

    // ---- epilogue: C/D map col=lane&15, row=(lane>>4)*4+reg
    const int r0 = (lane >> 4) * 4;
    const long long rowbase = m0 + wr * 128 + r0;
    const long long colbase = n0 + wc * 64 + ml;
    if (MODE == 1 || MODE == 2) {
#pragma unroll
        for (int i = 0; i < 8; ++i) {
            const long long rowb = rowbase + i * 16;
#pragma unroll
            for (int j = 0; j < 4; ++j) {
                const long long col = colbase + j * 16;
                const float bj = bias[col];
#pragma unroll
                for (int q = 0; q < 4; ++q) {
                    const float vv = acc[i][j][q] + bj;
                    Ch[(rowb + q) * (long long)ldc + col] = (MODE == 1) ? f2h(vv) : f2bf(vv);
                }
            }
        }
    } else if (MODE == 3) {
        Ch += (long long)bz * sC;
#pragma unroll
        for (int i = 0; i < 8; ++i) {
            const long long rowb = rowbase + i * 16;
#pragma unroll
            for (int j = 0; j < 4; ++j) {
                const long long col = colbase + j * 16;
#pragma unroll
                for (int q = 0; q < 4; ++q)
                    Ch[(rowb + q) * (long long)ldc + col] = f2bf(__expf(acc[i][j][q]));
            }
        }
    } else {   // MODE 4
        Cf += (long long)bz * sC;
        rvec += (long long)bz * sR;
#pragma unroll
        for (int i = 0; i < 8; ++i) {
            const long long rowb = rowbase + i * 16;
#pragma unroll
            for (int j = 0; j < 4; ++j) {
                const long long col = colbase + j * 16;
#pragma unroll
                for (int q = 0; q < 4; ++q)
                    Cf[(rowb + q) * (long long)ldc + col] = acc[i][j][q] * rvec[rowb + q];
            }
        }
    }
}

// f32 -> fp16 convert, 4 elems/thread, two source buffers in one launch
__global__ __launch_bounds__(256)
void cvt_f16_2(const float* __restrict__ a, long long na4,
               const float* __restrict__ b, long long nb4,
               unsigned short* __restrict__ oa, unsigned short* __restrict__ ob)
{
    const long long i = (long long)blockIdx.x * 256 + threadIdx.x;
    const float4* src;
    h16x4* dst;
    long long idx;
    if (i < na4)            { src = (const float4*)a; dst = (h16x4*)oa; idx = i; }
    else if (i < na4 + nb4) { src = (const float4*)b; dst = (h16x4*)ob; idx = i - na4; }
    else return;
    const float4 v = src[idx];
    h16x4 o;
    o.x = (_Float16)v.x; o.y = (_Float16)v.y;
    o.z = (_Float16)v.z; o.w = (_Float16)v.w;
    dst[idx] = o;
}

// vt[b][h][n] = v[b*2048+n][h]   (V transpose, bf16)
__global__ __launch_bounds__(256)
void transpose_v(const unsigned short* __restrict__ v, unsigned short* __restrict__ vt)
{
    __shared__ unsigned short t[32][33];
    const int b = blockIdx.z;
    const int n0 = blockIdx.x * 32, h0 = blockIdx.y * 32;
    const int tx = threadIdx.x, ty = threadIdx.y;      // 32 x 8
    const unsigned short* src = v + (long long)b * 2048 * 768;
#pragma unroll
    for (int q = 0; q < 4; ++q)
        t[ty + q * 8][tx] = src[(long long)(n0 + ty + q * 8) * 768 + h0 + tx];
    __syncthreads();
    unsigned short* dst = vt + ((long long)b * 768 + h0) * 2048 + n0;
#pragma unroll
    for (int q = 0; q < 4; ++q)
        dst[(long long)(ty + q * 8) * 2048 + tx] = t[tx][ty + q * 8];
}

// r[row] = 1 / sum(E[row][0:2048])   (E bf16, one 256-thr block per row)
__global__ __launch_bounds__(256)
void rowsum_recip(const unsigned short* __restrict__ E, float* __restrict__ r)
{
    const long long row = blockIdx.x;
    const int t = threadIdx.x, lane = t & 63, w = t >> 6;
    __shared__ float red[4];
    const uint4 v = ((const uint4*)(E + row * 2048))[t];   // 8 bf16
    float s = bf2f((unsigned short)(v.x & 0xffff)) + bf2f((unsigned short)(v.x >> 16))
            + bf2f((unsigned short)(v.y & 0xffff)) + bf2f((unsigned short)(v.y >> 16))
            + bf2f((unsigned short)(v.z & 0xffff)) + bf2f((unsigned short)(v.z >> 16))
            + bf2f((unsigned short)(v.w & 0xffff)) + bf2f((unsigned short)(v.w >> 16));
#pragma unroll
    for (int o = 32; o; o >>= 1) s += __shfl_xor(s, o);
    if (lane == 0) red[w] = s;
    __syncthreads();
    if (t == 0) r[row] = 1.f / ((red[0] + red[1]) + (red[2] + red[3]));
}

extern "C" void kernel_launch(void* const* d_in, const int* in_sizes, int n_in,
                              void* d_out, int out_size, void* d_ws, size_t ws_size,
                              hipStream_t stream)
{
    const float* x    = (const float*)d_in[0];   // [16384, 768]
    const float* W    = (const float*)d_in[1];   // [2304, 768]
    const float* bias = (const float*)d_in[2];   // [2304]
    float* out = (float*)d_out;                  // [8, 2048, 768]

    // ---- workspace layout (bytes), total 196.5 MB
    char* ws = (char*)d_ws;
    unsigned short* xh = (unsigned short*)ws;                      // [16384,768] fp16
    unsigned short* Wh = (unsigned short*)(ws + 25165824LL);       // [2304,768] fp16
    unsigned short* qk = (unsigned short*)(ws + 28704768LL);       // [16384,1536] fp16
    unsigned short* v  = (unsigned short*)(ws + 79036416LL);       // [16384,768] bf16
    unsigned short* vt = (unsigned short*)(ws + 104202240LL);      // [8,768,2048] bf16
    unsigned short* E  = (unsigned short*)(ws + 129368064LL);      // [8,2048,2048] bf16
    float*          r  = (float*)(ws + 196476928LL);               // [16384] f32

    // C1+C2: convert x and W to fp16 in one launch
    cvt_f16_2<<<dim3(14016), dim3(256), 0, stream>>>(
        x, 3145728LL, W, 442368LL, xh, Wh);

    // K1a: qk = x @ Wqk^T + b  (fp16, M=16384 N=1536 K=768), DEPTH3
    gemm_mfma<1, true, 2, 3><<<dim3(6, 64, 1), dim3(512), 0, stream>>>(
        xh, Wh, bias, nullptr, nullptr, qk,
        768, 768, 768, 1536, 0, 0, 0, 0);

    // K1b: v = x @ Wv^T + b -> bf16  (M=16384 N=768 K=768), DEPTH3
    gemm_mfma<2, true, 2, 3><<<dim3(3, 64, 1), dim3(512), 0, stream>>>(
        xh, Wh + 1536LL * 768, bias + 1536, nullptr, nullptr, v,
        768, 768, 768, 768, 0, 0, 0, 0);

    // T: vt = v^T per batch
    transpose_v<<<dim3(64, 24, 8), dim3(32, 8), 0, stream>>>(v, vt);

    // K2: E = exp(q @ k^T)  (fp16, M=N=2048 K=768, z=8), DEPTH2 (its best)
    gemm_mfma<3, true, 1, 2><<<dim3(8, 8, 8), dim3(512), 0, stream>>>(
        qk, qk + 768, nullptr, nullptr, nullptr, E,
        768, 1536, 1536, 2048,
        2048LL * 1536, 2048LL * 1536, 2048LL * 2048, 0);

    // K3': r = 1/rowsum(E)
    rowsum_recip<<<dim3(16384), dim3(256), 0, stream>>>(E, r);

    // K4: out = (E @ vt^T) * r[row]  (bf16, M=2048 N=768 K=2048, z=8), DEPTH3
    gemm_mfma<4, false, 1, 3><<<dim3(3, 8, 8), dim3(512), 0, stream>>>(
        E, vt, nullptr, r, out, nullptr,
        2048, 2048, 2048, 768,
        2048LL * 2048, 768LL * 2048, 2048LL * 768, 2048);
}